// Round 3
// baseline (315.779 us; speedup 1.0000x reference)
//
#include <hip/hip_runtime.h>

#define FSIZE   768
#define TW0     769
#define TW1     193
#define COL1    576
#define NPAIRS  300000
#define NCODES  30000
#define NPH0    12
#define NPH1    3
#define PPB     128                         // pairs per block (phase kernels)
#define PB      ((NPAIRS + PPB - 1) / PPB)  // 2344 blocks per phase
#define NFB     ((NPAIRS + 255) / 256)      // 1172 final-pass blocks

// ws layout (floats)
#define O_PART0  0
#define O_PART1  (O_PART0 + NPH0 * NPAIRS)      // 3,600,000
#define O_BIAS0  (O_PART1 + NPH1 * NPAIRS)      // +900,000
#define O_BIAS1  (O_BIAS0 + NCODES)
#define O_LOSSP  (O_BIAS1 + NCODES)
#define WS_FLOATS (O_LOSSP + NFB)
#define WS_NEEDED ((size_t)WS_FLOATS * 4)

__device__ __forceinline__ float loss_term(float x, float y) {
    float ax = fabsf(x);
    return fmaxf(x, 0.0f) + log1pf(__expf(-ax)) - x * y;
}

__device__ __forceinline__ float4 ld4u(const float* p) {
    float4 v; __builtin_memcpy(&v, p, 16); return v;
}

__global__ __launch_bounds__(256) void extract_bias_kernel(
    const float* __restrict__ w0, const float* __restrict__ w1,
    float* __restrict__ b0, float* __restrict__ b1)
{
    int i = blockIdx.x * 256 + threadIdx.x;
    if (i < NCODES) {
        b0[i] = w0[(size_t)i * TW0 + FSIZE];
        b1[i] = w1[(size_t)i * TW1 + (TW1 - 1)];
    }
}

// Task0 phase kernel: one dispatch, phase-major grid. Each 16-lane group does a
// 64-column partial dot for one pair; working set per phase ~10MB (L2/L3-hot).
__global__ __launch_bounds__(256) void phase0_kernel(
    const float* __restrict__ feat, const float* __restrict__ wt,
    const int* __restrict__ idx, float* __restrict__ part)
{
    const int bid  = blockIdx.x;
    const int ph   = bid / PB;
    const int pb   = bid - ph * PB;
    const int lane = threadIdx.x & 63;
    const int wv   = threadIdx.x >> 6;
    const int sub  = lane & 15;
    const int g    = lane >> 4;
    const int k0   = ph * 64;
    const int wbase = pb * PPB + wv * 32;
    float* pout = part + (size_t)ph * NPAIRS;

#pragma unroll
    for (int it = 0; it < 8; ++it) {
        const int pair = wbase + it * 4 + g;
        if (pair < NPAIRS) {
            const int r = idx[2 * pair];
            const int c = idx[2 * pair + 1];
            const float4 f = *(const float4*)(feat + (size_t)r * FSIZE + k0 + sub * 4);
            const float4 w = ld4u(wt + (size_t)c * TW0 + k0 + sub * 4);
            float s = f.x * w.x + f.y * w.y + f.z * w.z + f.w * w.w;
            s += __shfl_xor(s, 8, 64);
            s += __shfl_xor(s, 4, 64);
            s += __shfl_xor(s, 2, 64);
            s += __shfl_xor(s, 1, 64);
            if (sub == 0) pout[pair] = s;
        }
    }
}

// Task1 phase kernel: same structure, 3 phases over cols 576..767 / w1[0..191].
__global__ __launch_bounds__(256) void phase1_kernel(
    const float* __restrict__ feat, const float* __restrict__ wt,
    const int* __restrict__ idx, float* __restrict__ part)
{
    const int bid  = blockIdx.x;
    const int ph   = bid / PB;
    const int pb   = bid - ph * PB;
    const int lane = threadIdx.x & 63;
    const int wv   = threadIdx.x >> 6;
    const int sub  = lane & 15;
    const int g    = lane >> 4;
    const int k0   = ph * 64;
    const int wbase = pb * PPB + wv * 32;
    float* pout = part + (size_t)ph * NPAIRS;

#pragma unroll
    for (int it = 0; it < 8; ++it) {
        const int pair = wbase + it * 4 + g;
        if (pair < NPAIRS) {
            const int r = idx[2 * pair];
            const int c = idx[2 * pair + 1];
            const float4 f = *(const float4*)(feat + (size_t)r * FSIZE + COL1 + k0 + sub * 4);
            const float4 w = ld4u(wt + (size_t)c * TW1 + k0 + sub * 4);
            float s = f.x * w.x + f.y * w.y + f.z * w.z + f.w * w.w;
            s += __shfl_xor(s, 8, 64);
            s += __shfl_xor(s, 4, 64);
            s += __shfl_xor(s, 2, 64);
            s += __shfl_xor(s, 1, 64);
            if (sub == 0) pout[pair] = s;
        }
    }
}

__global__ __launch_bounds__(256) void final_kernel(
    const float* __restrict__ part0, const float* __restrict__ part1,
    const float* __restrict__ bias0, const float* __restrict__ bias1,
    const int* __restrict__ idx0, const float* __restrict__ y0,
    const int* __restrict__ idx1, const float* __restrict__ y1,
    float* __restrict__ out, float* __restrict__ lossp)
{
    __shared__ float sh[256];
    const int p = blockIdx.x * 256 + threadIdx.x;
    float l = 0.0f;
    if (p < NPAIRS) {
        float s0 = bias0[idx0[2 * p + 1]];
#pragma unroll
        for (int ph = 0; ph < NPH0; ++ph) s0 += part0[(size_t)ph * NPAIRS + p];
        out[p] = s0;
        l = loss_term(s0, y0[p]);

        float s1 = bias1[idx1[2 * p + 1]];
#pragma unroll
        for (int ph = 0; ph < NPH1; ++ph) s1 += part1[(size_t)ph * NPAIRS + p];
        l += loss_term(s1, y1[p]);
    }
    sh[threadIdx.x] = l;
    __syncthreads();
    for (int off = 128; off; off >>= 1) {
        if ((int)threadIdx.x < off) sh[threadIdx.x] += sh[threadIdx.x + off];
        __syncthreads();
    }
    if (threadIdx.x == 0) lossp[blockIdx.x] = sh[0];
}

__global__ __launch_bounds__(1024) void reduce_kernel(
    const float* __restrict__ partial, int n, float* __restrict__ out)
{
    __shared__ float sh[1024];
    float s = 0.0f;
    for (int i = threadIdx.x; i < n; i += 1024) s += partial[i];
    sh[threadIdx.x] = s;
    __syncthreads();
    for (int off = 512; off; off >>= 1) {
        if ((int)threadIdx.x < off) sh[threadIdx.x] += sh[threadIdx.x + off];
        __syncthreads();
    }
    if (threadIdx.x == 0) out[0] = sh[0];
}

// ---------------- fallback (unsorted, small-ws) ----------------
__global__ __launch_bounds__(256) void task0_kernel(
    const float* __restrict__ feat, const float* __restrict__ wt,
    const int* __restrict__ idx, const float* __restrict__ y,
    float* __restrict__ out_final, float* __restrict__ partial)
{
    __shared__ float lsum[4];
    const int lane = threadIdx.x & 63;
    const int wv = threadIdx.x >> 6;
    const int pair = blockIdx.x * 4 + wv;
    const int r = idx[2 * pair];
    const int c = idx[2 * pair + 1];
    const float4* f4 = (const float4*)(feat + (size_t)r * FSIZE);
    const float* wrow = wt + (size_t)c * TW0;
    float s = 0.0f;
#pragma unroll
    for (int k = 0; k < 3; ++k) {
        const int j = lane + (k << 6);
        float4 f = f4[j];
        float4 w = ld4u(wrow + 4 * j);
        s += f.x * w.x + f.y * w.y + f.z * w.z + f.w * w.w;
    }
#pragma unroll
    for (int m = 32; m; m >>= 1) s += __shfl_xor(s, m, 64);
    if (lane == 0) {
        const float logit = s + wrow[FSIZE];
        out_final[pair] = logit;
        lsum[wv] = loss_term(logit, y[pair]);
    }
    __syncthreads();
    if (threadIdx.x == 0)
        partial[blockIdx.x] = lsum[0] + lsum[1] + lsum[2] + lsum[3];
}

__global__ __launch_bounds__(256) void task1_kernel(
    const float* __restrict__ feat, const float* __restrict__ wt,
    const int* __restrict__ idx, const float* __restrict__ y,
    float* __restrict__ partial)
{
    __shared__ float lsum[16];
    const int lane = threadIdx.x & 63;
    const int wv = threadIdx.x >> 6;
    const int sub = lane & 15;
    const int pg = lane >> 4;
    const int pair = (blockIdx.x * 4 + wv) * 4 + pg;
    const int r = idx[2 * pair];
    const int c = idx[2 * pair + 1];
    const float4* f4 = (const float4*)(feat + (size_t)r * FSIZE + COL1);
    const float* wrow = wt + (size_t)c * TW1;
    float s = 0.0f;
#pragma unroll
    for (int k = 0; k < 3; ++k) {
        const int j = sub + (k << 4);
        float4 f = f4[j];
        float4 w = ld4u(wrow + 4 * j);
        s += f.x * w.x + f.y * w.y + f.z * w.z + f.w * w.w;
    }
#pragma unroll
    for (int m = 8; m; m >>= 1) s += __shfl_xor(s, m, 64);
    if (sub == 0) {
        const float logit = s + wrow[TW1 - 1];
        lsum[wv * 4 + pg] = loss_term(logit, y[pair]);
    }
    __syncthreads();
    if (threadIdx.x == 0) {
        float t = 0.0f;
#pragma unroll
        for (int i = 0; i < 16; ++i) t += lsum[i];
        partial[blockIdx.x] = t;
    }
}

extern "C" void kernel_launch(void* const* d_in, const int* in_sizes, int n_in,
                              void* d_out, int out_size, void* d_ws, size_t ws_size,
                              hipStream_t stream) {
    const float* feat = (const float*)d_in[0];
    const float* w0   = (const float*)d_in[1];
    const float* w1   = (const float*)d_in[2];
    const int*   idx0 = (const int*)d_in[3];
    const float* y0   = (const float*)d_in[4];
    const int*   idx1 = (const int*)d_in[6];
    const float* y1   = (const float*)d_in[7];

    float* out = (float*)d_out;
    float* ws  = (float*)d_ws;

    if (ws_size >= WS_NEEDED) {
        float* part0 = ws + O_PART0;
        float* part1 = ws + O_PART1;
        float* b0    = ws + O_BIAS0;
        float* b1    = ws + O_BIAS1;
        float* lossp = ws + O_LOSSP;

        extract_bias_kernel<<<(NCODES + 255) / 256, 256, 0, stream>>>(w0, w1, b0, b1);
        phase0_kernel<<<NPH0 * PB, 256, 0, stream>>>(feat, w0, idx0, part0);
        phase1_kernel<<<NPH1 * PB, 256, 0, stream>>>(feat, w1, idx1, part1);
        final_kernel<<<NFB, 256, 0, stream>>>(part0, part1, b0, b1,
                                              idx0, y0, idx1, y1, out, lossp);
        reduce_kernel<<<1, 1024, 0, stream>>>(lossp, NFB, out + NPAIRS);
    } else {
        float* part = ws;
        const int nb0 = NPAIRS / 4;
        const int nb1 = NPAIRS / 16;
        task0_kernel<<<nb0, 256, 0, stream>>>(feat, w0, idx0, y0, out, part);
        task1_kernel<<<nb1, 256, 0, stream>>>(feat, w1, idx1, y1, part + nb0);
        reduce_kernel<<<1, 1024, 0, stream>>>(part, nb0 + nb1, out + NPAIRS);
    }
}

// Round 4
// 202.895 us; speedup vs baseline: 1.5564x; 1.5564x over previous
//
#include <hip/hip_runtime.h>
#include <hip/hip_fp16.h>

#define FSIZE   768
#define TW0     769
#define TW1     193
#define COL1    576
#define NPAIRS  300000
#define NCODES  30000
#define NROWS   8192
#define W1STRIDE 200
#define CHUNK   16
#define NWAVES0 (NPAIRS / CHUNK)            // 18750
#define NB0     ((NWAVES0 + 3) / 4)         // 4688
#define NWAVES0_PAD (NB0 * 4)               // 18752
#define NB1     (NPAIRS / 16)               // 18750
#define NPART   (NWAVES0_PAD + NB1)

#define SZ_FEAT16 (NROWS * FSIZE / 2)       // halfs stored as float-slots: 3,145,728
#define SZ_W116   (NCODES * W1STRIDE / 2)   // 3,000,000

__device__ __forceinline__ float loss_term(float x, float y) {
    float ax = fabsf(x);
    return fmaxf(x, 0.0f) + log1pf(__expf(-ax)) - x * y;
}

__device__ __forceinline__ float4 ld4u(const float* p) {
    float4 v; __builtin_memcpy(&v, p, 16); return v;
}

// fp16x4 (as uint2) dot f32x4
__device__ __forceinline__ float dot4h(uint2 u, float4 w) {
    __half2 h0 = *reinterpret_cast<const __half2*>(&u.x);
    __half2 h1 = *reinterpret_cast<const __half2*>(&u.y);
    float2 a = __half22float2(h0), b = __half22float2(h1);
    return a.x * w.x + a.y * w.y + b.x * w.z + b.y * w.w;
}

// fp16x4 dot fp16x4
__device__ __forceinline__ float dot4hh(uint2 u, uint2 v) {
    __half2 a0 = *reinterpret_cast<const __half2*>(&u.x);
    __half2 a1 = *reinterpret_cast<const __half2*>(&u.y);
    __half2 b0 = *reinterpret_cast<const __half2*>(&v.x);
    __half2 b1 = *reinterpret_cast<const __half2*>(&v.y);
    float2 fa0 = __half22float2(a0), fa1 = __half22float2(a1);
    float2 fb0 = __half22float2(b0), fb1 = __half22float2(b1);
    return fa0.x * fb0.x + fa0.y * fb0.y + fa1.x * fb1.x + fa1.y * fb1.y;
}

__global__ __launch_bounds__(256) void conv_feat_kernel(
    const float* __restrict__ in, __half* __restrict__ out)
{
    int i = (blockIdx.x * 256 + threadIdx.x) * 4;
    if (i < NROWS * FSIZE) {
        float4 v = *(const float4*)(in + i);
        *(__half2*)(out + i)     = __floats2half2_rn(v.x, v.y);
        *(__half2*)(out + i + 2) = __floats2half2_rn(v.z, v.w);
    }
}

__global__ __launch_bounds__(256) void conv_w1_kernel(
    const float* __restrict__ w1, __half* __restrict__ out)
{
    int i = blockIdx.x * 256 + threadIdx.x;
    if (i < NCODES * W1STRIDE) {
        int c = i / W1STRIDE;
        int e = i - c * W1STRIDE;
        float v = (e < TW1) ? w1[(size_t)c * TW1 + e] : 0.0f;
        out[i] = __float2half(v);
    }
}

__global__ __launch_bounds__(256) void zero_cnt_kernel(int* __restrict__ cnt) {
    int i = blockIdx.x * 256 + threadIdx.x;
    if (i < NCODES) cnt[i] = 0;
}

__global__ __launch_bounds__(256) void hist_kernel(const int* __restrict__ idx,
                                                   int* __restrict__ cnt) {
    int p = blockIdx.x * 256 + threadIdx.x;
    if (p < NPAIRS) atomicAdd(&cnt[idx[2 * p + 1]], 1);
}

__global__ __launch_bounds__(1024) void scan_kernel(const int* __restrict__ cnt,
                                                    int* __restrict__ cursor) {
    __shared__ int sh[1024];
    const int t = threadIdx.x;
    const int base = t * 30;
    int local[30];
    int s = 0;
#pragma unroll
    for (int j = 0; j < 30; ++j) {
        int v = (base + j < NCODES) ? cnt[base + j] : 0;
        local[j] = s; s += v;
    }
    sh[t] = s;
    __syncthreads();
    for (int off = 1; off < 1024; off <<= 1) {
        int v = (t >= off) ? sh[t - off] : 0;
        __syncthreads();
        sh[t] += v;
        __syncthreads();
    }
    const int chunkbase = sh[t] - s;
#pragma unroll
    for (int j = 0; j < 30; ++j)
        if (base + j < NCODES) cursor[base + j] = chunkbase + local[j];
}

__global__ __launch_bounds__(256) void scatter_kernel(const int* __restrict__ idx,
                                                      int* __restrict__ cursor,
                                                      int* __restrict__ sorted) {
    int p = blockIdx.x * 256 + threadIdx.x;
    if (p < NPAIRS) {
        int c = idx[2 * p + 1];
        int pos = atomicAdd(&cursor[c], 1);
        sorted[pos] = p;
    }
}

// Task0: code-sorted, w0 (f32) register-cached across same-code runs,
// features gathered as fp16 (24 lines/pair instead of 48).
__global__ __launch_bounds__(256) void task0_sorted_h_kernel(
    const __half* __restrict__ feat16, const float* __restrict__ wt,
    const int* __restrict__ idx, const float* __restrict__ y,
    const int* __restrict__ sorted,
    float* __restrict__ out_final, float* __restrict__ partial)
{
    const int lane = threadIdx.x & 63;
    const int wid = blockIdx.x * 4 + (threadIdx.x >> 6);
    if (wid >= NWAVES0) { if (lane == 0) partial[wid] = 0.0f; return; }
    const int base = wid * CHUNK;

    const int pb = sorted[base + (lane & 15)];
    const int sel = lane >> 4;
    int g;
    if (sel == 0)      g = idx[2 * pb];
    else if (sel == 1) g = idx[2 * pb + 1];
    else if (sel == 2) g = __float_as_int(y[pb]);
    else               g = 0;

    float lossacc = 0.0f;
    int prev_c = -1;
    float4 w0, w1, w2; float wb = 0.0f;

    for (int i = 0; i < CHUNK; ++i) {
        const int r = __shfl(g, i, 64);
        const int c = __shfl(g, 16 + i, 64);
        const float yv = __int_as_float(__shfl(g, 32 + i, 64));

        if (c != prev_c) {                   // wave-uniform
            prev_c = c;
            const float* wrow = wt + (size_t)c * TW0;
            w0 = ld4u(wrow + 4 * lane);
            w1 = ld4u(wrow + 4 * lane + 256);
            w2 = ld4u(wrow + 4 * lane + 512);
            wb = wrow[FSIZE];
        }
        const __half* fr = feat16 + (size_t)r * FSIZE;
        uint2 f0 = *(const uint2*)(fr + 4 * lane);
        uint2 f1 = *(const uint2*)(fr + 256 + 4 * lane);
        uint2 f2 = *(const uint2*)(fr + 512 + 4 * lane);

        float s = dot4h(f0, w0) + dot4h(f1, w1) + dot4h(f2, w2);
#pragma unroll
        for (int m = 32; m; m >>= 1) s += __shfl_xor(s, m, 64);

        const float logit = s + wb;
        lossacc += loss_term(logit, yv);
        if (lane == 0) out_final[__shfl(pb, i, 64)] = logit;
    }
    if (lane == 0) partial[wid] = lossacc;
}

// Task1: unsorted, 16 lanes/pair; feat fp16; w1 fp16 (tier A) or f32 (tier B).
template <bool W1H>
__global__ __launch_bounds__(256) void task1_h_kernel(
    const __half* __restrict__ feat16, const float* __restrict__ w1f,
    const __half* __restrict__ w116,
    const int* __restrict__ idx, const float* __restrict__ y,
    float* __restrict__ partial)
{
    __shared__ float lsum[16];
    const int lane = threadIdx.x & 63;
    const int wv = threadIdx.x >> 6;
    const int sub = lane & 15;
    const int pg = lane >> 4;
    const int pair = (blockIdx.x * 4 + wv) * 4 + pg;

    const int r = idx[2 * pair];
    const int c = idx[2 * pair + 1];
    const __half* fr = feat16 + (size_t)r * FSIZE + COL1;
    uint2 f0 = *(const uint2*)(fr + 4 * sub);
    uint2 f1 = *(const uint2*)(fr + 64 + 4 * sub);
    uint2 f2 = *(const uint2*)(fr + 128 + 4 * sub);

    float s, bias;
    if (W1H) {
        const __half* wr = w116 + (size_t)c * W1STRIDE;
        s = dot4hh(f0, *(const uint2*)(wr + 4 * sub))
          + dot4hh(f1, *(const uint2*)(wr + 64 + 4 * sub))
          + dot4hh(f2, *(const uint2*)(wr + 128 + 4 * sub));
        bias = __half2float(wr[192]);
    } else {
        const float* wr = w1f + (size_t)c * TW1;
        s = dot4h(f0, ld4u(wr + 4 * sub))
          + dot4h(f1, ld4u(wr + 64 + 4 * sub))
          + dot4h(f2, ld4u(wr + 128 + 4 * sub));
        bias = wr[192];
    }
#pragma unroll
    for (int m = 8; m; m >>= 1) s += __shfl_xor(s, m, 64);

    if (sub == 0) lsum[wv * 4 + pg] = loss_term(s + bias, y[pair]);
    __syncthreads();
    if (threadIdx.x == 0) {
        float t = 0.0f;
#pragma unroll
        for (int i = 0; i < 16; ++i) t += lsum[i];
        partial[blockIdx.x] = t;
    }
}

__global__ __launch_bounds__(1024) void reduce_kernel(
    const float* __restrict__ partial, int n, float* __restrict__ out)
{
    __shared__ float sh[1024];
    float s = 0.0f;
    for (int i = threadIdx.x; i < n; i += 1024) s += partial[i];
    sh[threadIdx.x] = s;
    __syncthreads();
    for (int off = 512; off; off >>= 1) {
        if ((int)threadIdx.x < off) sh[threadIdx.x] += sh[threadIdx.x + off];
        __syncthreads();
    }
    if (threadIdx.x == 0) out[0] = sh[0];
}

// ---------------- tier C fallback (all-f32, unsorted) ----------------
__global__ __launch_bounds__(256) void task0_kernel(
    const float* __restrict__ feat, const float* __restrict__ wt,
    const int* __restrict__ idx, const float* __restrict__ y,
    float* __restrict__ out_final, float* __restrict__ partial)
{
    __shared__ float lsum[4];
    const int lane = threadIdx.x & 63;
    const int wv = threadIdx.x >> 6;
    const int pair = blockIdx.x * 4 + wv;
    const int r = idx[2 * pair];
    const int c = idx[2 * pair + 1];
    const float4* f4 = (const float4*)(feat + (size_t)r * FSIZE);
    const float* wrow = wt + (size_t)c * TW0;
    float s = 0.0f;
#pragma unroll
    for (int k = 0; k < 3; ++k) {
        const int j = lane + (k << 6);
        float4 f = f4[j];
        float4 w = ld4u(wrow + 4 * j);
        s += f.x * w.x + f.y * w.y + f.z * w.z + f.w * w.w;
    }
#pragma unroll
    for (int m = 32; m; m >>= 1) s += __shfl_xor(s, m, 64);
    if (lane == 0) {
        const float logit = s + wrow[FSIZE];
        out_final[pair] = logit;
        lsum[wv] = loss_term(logit, y[pair]);
    }
    __syncthreads();
    if (threadIdx.x == 0)
        partial[blockIdx.x] = lsum[0] + lsum[1] + lsum[2] + lsum[3];
}

__global__ __launch_bounds__(256) void task1_kernel(
    const float* __restrict__ feat, const float* __restrict__ wt,
    const int* __restrict__ idx, const float* __restrict__ y,
    float* __restrict__ partial)
{
    __shared__ float lsum[16];
    const int lane = threadIdx.x & 63;
    const int wv = threadIdx.x >> 6;
    const int sub = lane & 15;
    const int pg = lane >> 4;
    const int pair = (blockIdx.x * 4 + wv) * 4 + pg;
    const int r = idx[2 * pair];
    const int c = idx[2 * pair + 1];
    const float4* f4 = (const float4*)(feat + (size_t)r * FSIZE + COL1);
    const float* wrow = wt + (size_t)c * TW1;
    float s = 0.0f;
#pragma unroll
    for (int k = 0; k < 3; ++k) {
        const int j = sub + (k << 4);
        float4 f = f4[j];
        float4 w = ld4u(wrow + 4 * j);
        s += f.x * w.x + f.y * w.y + f.z * w.z + f.w * w.w;
    }
#pragma unroll
    for (int m = 8; m; m >>= 1) s += __shfl_xor(s, m, 64);
    if (sub == 0) {
        const float logit = s + wrow[TW1 - 1];
        lsum[wv * 4 + pg] = loss_term(logit, y[pair]);
    }
    __syncthreads();
    if (threadIdx.x == 0) {
        float t = 0.0f;
#pragma unroll
        for (int i = 0; i < 16; ++i) t += lsum[i];
        partial[blockIdx.x] = t;
    }
}

extern "C" void kernel_launch(void* const* d_in, const int* in_sizes, int n_in,
                              void* d_out, int out_size, void* d_ws, size_t ws_size,
                              hipStream_t stream) {
    const float* feat = (const float*)d_in[0];
    const float* w0   = (const float*)d_in[1];
    const float* w1   = (const float*)d_in[2];
    const int*   idx0 = (const int*)d_in[3];
    const float* y0   = (const float*)d_in[4];
    const int*   idx1 = (const int*)d_in[6];
    const float* y1   = (const float*)d_in[7];

    float* out = (float*)d_out;
    float* ws  = (float*)d_ws;

    const size_t commonFloats = (size_t)NCODES * 2 + NPAIRS + NPART + 64;
    const size_t needA = (SZ_FEAT16 + SZ_W116 + commonFloats) * 4;
    const size_t needB = (SZ_FEAT16 + commonFloats) * 4;

    if (ws_size >= needB) {
        const bool tierA = (ws_size >= needA);
        size_t off = 0;
        __half* feat16 = (__half*)(ws + off); off += SZ_FEAT16;
        __half* w116 = nullptr;
        if (tierA) { w116 = (__half*)(ws + off); off += SZ_W116; }
        int* cnt    = (int*)(ws + off); off += NCODES;
        int* cursor = (int*)(ws + off); off += NCODES;
        int* sorted = (int*)(ws + off); off += NPAIRS;
        float* part = ws + off;

        conv_feat_kernel<<<NROWS * FSIZE / 4 / 256, 256, 0, stream>>>(feat, feat16);
        if (tierA)
            conv_w1_kernel<<<(NCODES * W1STRIDE + 255) / 256, 256, 0, stream>>>(w1, w116);
        zero_cnt_kernel<<<(NCODES + 255) / 256, 256, 0, stream>>>(cnt);
        hist_kernel<<<(NPAIRS + 255) / 256, 256, 0, stream>>>(idx0, cnt);
        scan_kernel<<<1, 1024, 0, stream>>>(cnt, cursor);
        scatter_kernel<<<(NPAIRS + 255) / 256, 256, 0, stream>>>(idx0, cursor, sorted);
        task0_sorted_h_kernel<<<NB0, 256, 0, stream>>>(feat16, w0, idx0, y0, sorted,
                                                       out, part);
        if (tierA)
            task1_h_kernel<true><<<NB1, 256, 0, stream>>>(feat16, w1, w116, idx1, y1,
                                                          part + NWAVES0_PAD);
        else
            task1_h_kernel<false><<<NB1, 256, 0, stream>>>(feat16, w1, nullptr, idx1, y1,
                                                           part + NWAVES0_PAD);
        reduce_kernel<<<1, 1024, 0, stream>>>(part, NPART, out + NPAIRS);
    } else {
        float* part = ws;
        const int nb0 = NPAIRS / 4;
        task0_kernel<<<nb0, 256, 0, stream>>>(feat, w0, idx0, y0, out, part);
        task1_kernel<<<NB1, 256, 0, stream>>>(feat, w1, idx1, y1, part + nb0);
        reduce_kernel<<<1, 1024, 0, stream>>>(part, nb0 + NB1, out + NPAIRS);
    }
}

// Round 5
// 187.022 us; speedup vs baseline: 1.6885x; 1.0849x over previous
//
#include <hip/hip_runtime.h>
#include <hip/hip_fp16.h>

#define FSIZE   768
#define TW0     769
#define TW1     193
#define COL1    576
#define NPAIRS  300000
#define NCODES  30000
#define NROWS   8192
#define W1STRIDE 200
#define NCB     32768                       // padded histogram bins
#define CHUNK   16
#define NWAVES0 (NPAIRS / CHUNK)            // 18750
#define NB0     ((NWAVES0 + 3) / 4)         // 4688
#define NWAVES0_PAD (NB0 * 4)               // 18752
#define NB1     (NPAIRS / 16)               // 18750
#define NPART   (NWAVES0_PAD + NB1 * 4)     // 18752 + 75000

#define SZ_FEAT16 (NROWS * FSIZE / 2)       // in 4B units
#define SZ_W116   (NCODES * W1STRIDE / 2)

typedef _Float16 h2_t __attribute__((ext_vector_type(2)));

#if defined(__has_builtin)
# if __has_builtin(__builtin_amdgcn_fdot2)
#  define HAVE_FDOT2 1
# endif
#endif

__device__ __forceinline__ float fdot2f(h2_t a, h2_t b, float c) {
#ifdef HAVE_FDOT2
    return __builtin_amdgcn_fdot2(a, b, c, false);
#else
    return (float)a[0] * (float)b[0] + (float)a[1] * (float)b[1] + c;
#endif
}

__device__ __forceinline__ float loss_term(float x, float y) {
    float ax = fabsf(x);
    return fmaxf(x, 0.0f) + log1pf(__expf(-ax)) - x * y;
}

__device__ __forceinline__ float4 ld4u(const float* p) {
    float4 v; __builtin_memcpy(&v, p, 16); return v;
}

__device__ __forceinline__ void ld2h(const __half* p, h2_t& a, h2_t& b) {
    uint2 u = *(const uint2*)p;
    __builtin_memcpy(&a, &u.x, 4);
    __builtin_memcpy(&b, &u.y, 4);
}

// K1: feat f32 -> fp16, fused with histogram zeroing
__global__ __launch_bounds__(256) void conv_feat_kernel(
    const float* __restrict__ in, __half* __restrict__ out, int* __restrict__ cnt)
{
    const int gid = blockIdx.x * 256 + threadIdx.x;
    const int i = gid * 4;
    if (i < NROWS * FSIZE) {
        float4 v = *(const float4*)(in + i);
        __half2* o = (__half2*)(out + i);
        o[0] = __floats2half2_rn(v.x, v.y);
        o[1] = __floats2half2_rn(v.z, v.w);
    }
    if (gid < NCB) cnt[gid] = 0;
}

// K2: w1 f32 -> fp16 (padded stride 200), fused with task0-code histogram
__global__ __launch_bounds__(256) void conv_w1_hist_kernel(
    const float* __restrict__ w1, __half* __restrict__ out,
    const int* __restrict__ idx0, int* __restrict__ cnt)
{
    const int gid = blockIdx.x * 256 + threadIdx.x;
    const int i4 = gid * 4;
    if (i4 < NCODES * W1STRIDE) {
        const int c = i4 / W1STRIDE;
        const int e = i4 - c * W1STRIDE;
        const float* src = w1 + (size_t)c * TW1;
        float v0 = 0.f, v1 = 0.f, v2 = 0.f, v3 = 0.f;
        if (e + 3 < TW1) {
            float4 f = ld4u(src + e);
            v0 = f.x; v1 = f.y; v2 = f.z; v3 = f.w;
        } else {
            if (e     < TW1) v0 = src[e];
            if (e + 1 < TW1) v1 = src[e + 1];
            if (e + 2 < TW1) v2 = src[e + 2];
        }
        __half2* dst = (__half2*)(out + i4);
        dst[0] = __floats2half2_rn(v0, v1);
        dst[1] = __floats2half2_rn(v2, v3);
    }
    if (gid < NPAIRS) atomicAdd(&cnt[idx0[2 * gid + 1]], 1);
}

__global__ __launch_bounds__(256) void hist_kernel(const int* __restrict__ idx,
                                                   int* __restrict__ cnt) {
    int p = blockIdx.x * 256 + threadIdx.x;
    if (p < NPAIRS) atomicAdd(&cnt[idx[2 * p + 1]], 1);
}

// K3: exclusive scan over 32768 bins, 1 block, vectorized
__global__ __launch_bounds__(1024) void scan_kernel(const int* __restrict__ cnt,
                                                    int* __restrict__ cursor) {
    __shared__ int sh[1024];
    const int t = threadIdx.x;
    const int4* c4 = (const int4*)cnt + t * 8;
    int4 v[8];
#pragma unroll
    for (int j = 0; j < 8; ++j) v[j] = c4[j];
    int loc[32];
    int s = 0;
#pragma unroll
    for (int j = 0; j < 8; ++j) {
        loc[4 * j + 0] = s; s += v[j].x;
        loc[4 * j + 1] = s; s += v[j].y;
        loc[4 * j + 2] = s; s += v[j].z;
        loc[4 * j + 3] = s; s += v[j].w;
    }
    sh[t] = s;
    __syncthreads();
    for (int off = 1; off < 1024; off <<= 1) {
        int u = (t >= off) ? sh[t - off] : 0;
        __syncthreads();
        sh[t] += u;
        __syncthreads();
    }
    const int base = sh[t] - s;
    int4* cu = (int4*)cursor + t * 8;
#pragma unroll
    for (int j = 0; j < 8; ++j)
        cu[j] = make_int4(base + loc[4 * j], base + loc[4 * j + 1],
                          base + loc[4 * j + 2], base + loc[4 * j + 3]);
}

// K4: scatter packed records {r, c, y_bits, p}
__global__ __launch_bounds__(256) void scatter_kernel(
    const int* __restrict__ idx, const float* __restrict__ y,
    int* __restrict__ cursor, uint4* __restrict__ srec)
{
    int p = blockIdx.x * 256 + threadIdx.x;
    if (p < NPAIRS) {
        int r = idx[2 * p];
        int c = idx[2 * p + 1];
        int pos = atomicAdd(&cursor[c], 1);
        srec[pos] = make_uint4((unsigned)r, (unsigned)c, __float_as_uint(y[p]), (unsigned)p);
    }
}

// K5: merged main kernel. Blocks [0, NB0): task0 (code-sorted, fdot2, loss-dedup).
//     Blocks [NB0, NB0+NB1): task1 (16 lanes/pair, fdot2).
template <bool W1H>
__global__ __launch_bounds__(256) void main_kernel(
    const __half* __restrict__ feat16, const float* __restrict__ w0,
    const float* __restrict__ w1f, const __half* __restrict__ w116,
    const uint4* __restrict__ srec,
    const int* __restrict__ idx1, const float* __restrict__ y1,
    float* __restrict__ out_final, float* __restrict__ partial)
{
    const int lane = threadIdx.x & 63;
    const int wv   = threadIdx.x >> 6;

    if (blockIdx.x < NB0) {
        const int wid = blockIdx.x * 4 + wv;
        if (wid >= NWAVES0) { if (lane == 0) partial[wid] = 0.f; return; }
        const uint4 rec = srec[wid * CHUNK + (lane & 15)];

        float lg = 0.f;
        int prev_c = -1;
        h2_t wh0, wh1, wh2, wh3, wh4, wh5;
        float wb = 0.f;

#pragma unroll
        for (int i = 0; i < CHUNK; ++i) {
            const int r = __shfl((int)rec.x, i, 64);
            const int c = __shfl((int)rec.y, i, 64);
            if (c != prev_c) {                     // wave-uniform (sorted by code)
                prev_c = c;
                const float* wrow = w0 + (size_t)c * TW0;
                float4 A = ld4u(wrow + 4 * lane);
                float4 B = ld4u(wrow + 4 * lane + 256);
                float4 C = ld4u(wrow + 4 * lane + 512);
                wh0[0] = (_Float16)A.x; wh0[1] = (_Float16)A.y;
                wh1[0] = (_Float16)A.z; wh1[1] = (_Float16)A.w;
                wh2[0] = (_Float16)B.x; wh2[1] = (_Float16)B.y;
                wh3[0] = (_Float16)B.z; wh3[1] = (_Float16)B.w;
                wh4[0] = (_Float16)C.x; wh4[1] = (_Float16)C.y;
                wh5[0] = (_Float16)C.z; wh5[1] = (_Float16)C.w;
                wb = wrow[FSIZE];
            }
            const __half* fr = feat16 + (size_t)r * FSIZE + 4 * lane;
            h2_t a0, a1, a2, a3, a4, a5;
            ld2h(fr, a0, a1);
            ld2h(fr + 256, a2, a3);
            ld2h(fr + 512, a4, a5);
            float s = fdot2f(a0, wh0, 0.f);
            s = fdot2f(a1, wh1, s);
            s = fdot2f(a2, wh2, s);
            s = fdot2f(a3, wh3, s);
            s = fdot2f(a4, wh4, s);
            s = fdot2f(a5, wh5, s);
#pragma unroll
            for (int m = 32; m; m >>= 1) s += __shfl_xor(s, m, 64);
            s += wb;
            lg = (lane == i) ? s : lg;             // pair i's logit parks in lane i
        }

        float ll = 0.f;
        if (lane < 16) {
            out_final[rec.w] = lg;                 // one scattered store, 16 pairs
            ll = loss_term(lg, __uint_as_float(rec.z));  // one loss pass, 16 pairs
        }
#pragma unroll
        for (int m = 32; m; m >>= 1) ll += __shfl_xor(ll, m, 64);
        if (lane == 0) partial[wid] = ll;
    } else {
        const int bid  = blockIdx.x - NB0;
        const int sub  = lane & 15;
        const int pair = (bid * 4 + wv) * 4 + (lane >> 4);

        const int r = idx1[2 * pair];
        const int c = idx1[2 * pair + 1];
        const __half* fr = feat16 + (size_t)r * FSIZE + COL1 + 4 * sub;
        h2_t a0, a1, a2, a3, a4, a5;
        ld2h(fr, a0, a1);
        ld2h(fr + 64, a2, a3);
        ld2h(fr + 128, a4, a5);

        float s, bias;
        if (W1H) {
            const __half* wr = w116 + (size_t)c * W1STRIDE;
            h2_t b0, b1, b2, b3, b4, b5;
            ld2h(wr + 4 * sub, b0, b1);
            ld2h(wr + 64 + 4 * sub, b2, b3);
            ld2h(wr + 128 + 4 * sub, b4, b5);
            s = fdot2f(a0, b0, 0.f);
            s = fdot2f(a1, b1, s);
            s = fdot2f(a2, b2, s);
            s = fdot2f(a3, b3, s);
            s = fdot2f(a4, b4, s);
            s = fdot2f(a5, b5, s);
            bias = __half2float(wr[192]);
        } else {
            const float* wr = w1f + (size_t)c * TW1;
            float4 W0 = ld4u(wr + 4 * sub);
            float4 W1 = ld4u(wr + 64 + 4 * sub);
            float4 W2 = ld4u(wr + 128 + 4 * sub);
            s = (float)a0[0] * W0.x + (float)a0[1] * W0.y + (float)a1[0] * W0.z + (float)a1[1] * W0.w
              + (float)a2[0] * W1.x + (float)a2[1] * W1.y + (float)a3[0] * W1.z + (float)a3[1] * W1.w
              + (float)a4[0] * W2.x + (float)a4[1] * W2.y + (float)a5[0] * W2.z + (float)a5[1] * W2.w;
            bias = wr[192];
        }
#pragma unroll
        for (int m = 8; m; m >>= 1) s += __shfl_xor(s, m, 64);
        float ll = (sub == 0) ? loss_term(s + bias, y1[pair]) : 0.f;
#pragma unroll
        for (int m = 32; m; m >>= 1) ll += __shfl_xor(ll, m, 64);
        if (lane == 0) partial[NWAVES0_PAD + bid * 4 + wv] = ll;
    }
}

__global__ __launch_bounds__(1024) void reduce_kernel(
    const float* __restrict__ partial, int n, float* __restrict__ out)
{
    __shared__ float sh[1024];
    float s = 0.0f;
    for (int i = threadIdx.x; i < n; i += 1024) s += partial[i];
    sh[threadIdx.x] = s;
    __syncthreads();
    for (int off = 512; off; off >>= 1) {
        if ((int)threadIdx.x < off) sh[threadIdx.x] += sh[threadIdx.x + off];
        __syncthreads();
    }
    if (threadIdx.x == 0) out[0] = sh[0];
}

// ---------------- tier C fallback (all-f32, unsorted) ----------------
__global__ __launch_bounds__(256) void task0_kernel(
    const float* __restrict__ feat, const float* __restrict__ wt,
    const int* __restrict__ idx, const float* __restrict__ y,
    float* __restrict__ out_final, float* __restrict__ partial)
{
    __shared__ float lsum[4];
    const int lane = threadIdx.x & 63;
    const int wv = threadIdx.x >> 6;
    const int pair = blockIdx.x * 4 + wv;
    const int r = idx[2 * pair];
    const int c = idx[2 * pair + 1];
    const float4* f4 = (const float4*)(feat + (size_t)r * FSIZE);
    const float* wrow = wt + (size_t)c * TW0;
    float s = 0.0f;
#pragma unroll
    for (int k = 0; k < 3; ++k) {
        const int j = lane + (k << 6);
        float4 f = f4[j];
        float4 w = ld4u(wrow + 4 * j);
        s += f.x * w.x + f.y * w.y + f.z * w.z + f.w * w.w;
    }
#pragma unroll
    for (int m = 32; m; m >>= 1) s += __shfl_xor(s, m, 64);
    if (lane == 0) {
        const float logit = s + wrow[FSIZE];
        out_final[pair] = logit;
        lsum[wv] = loss_term(logit, y[pair]);
    }
    __syncthreads();
    if (threadIdx.x == 0)
        partial[blockIdx.x] = lsum[0] + lsum[1] + lsum[2] + lsum[3];
}

__global__ __launch_bounds__(256) void task1_kernel(
    const float* __restrict__ feat, const float* __restrict__ wt,
    const int* __restrict__ idx, const float* __restrict__ y,
    float* __restrict__ partial)
{
    __shared__ float lsum[16];
    const int lane = threadIdx.x & 63;
    const int wv = threadIdx.x >> 6;
    const int sub = lane & 15;
    const int pg = lane >> 4;
    const int pair = (blockIdx.x * 4 + wv) * 4 + pg;
    const int r = idx[2 * pair];
    const int c = idx[2 * pair + 1];
    const float4* f4 = (const float4*)(feat + (size_t)r * FSIZE + COL1);
    const float* wrow = wt + (size_t)c * TW1;
    float s = 0.0f;
#pragma unroll
    for (int k = 0; k < 3; ++k) {
        const int j = sub + (k << 4);
        float4 f = f4[j];
        float4 w = ld4u(wrow + 4 * j);
        s += f.x * w.x + f.y * w.y + f.z * w.z + f.w * w.w;
    }
#pragma unroll
    for (int m = 8; m; m >>= 1) s += __shfl_xor(s, m, 64);
    if (sub == 0) {
        const float logit = s + wrow[TW1 - 1];
        lsum[wv * 4 + pg] = loss_term(logit, y[pair]);
    }
    __syncthreads();
    if (threadIdx.x == 0) {
        float t = 0.0f;
#pragma unroll
        for (int i = 0; i < 16; ++i) t += lsum[i];
        partial[blockIdx.x] = t;
    }
}

extern "C" void kernel_launch(void* const* d_in, const int* in_sizes, int n_in,
                              void* d_out, int out_size, void* d_ws, size_t ws_size,
                              hipStream_t stream) {
    const float* feat = (const float*)d_in[0];
    const float* w0   = (const float*)d_in[1];
    const float* w1   = (const float*)d_in[2];
    const int*   idx0 = (const int*)d_in[3];
    const float* y0   = (const float*)d_in[4];
    const int*   idx1 = (const int*)d_in[6];
    const float* y1   = (const float*)d_in[7];

    float* out = (float*)d_out;
    float* ws  = (float*)d_ws;

    const size_t commonU = (size_t)NCB * 2 + (size_t)NPAIRS * 4 + NPART + 64;
    const size_t needA = (SZ_FEAT16 + SZ_W116 + commonU) * 4;
    const size_t needB = (SZ_FEAT16 + commonU) * 4;

    if (ws_size >= needB) {
        const bool tierA = (ws_size >= needA);
        size_t off = 0;
        __half* feat16 = (__half*)(ws + off); off += SZ_FEAT16;
        __half* w116 = nullptr;
        if (tierA) { w116 = (__half*)(ws + off); off += SZ_W116; }
        int* cnt    = (int*)(ws + off); off += NCB;
        int* cursor = (int*)(ws + off); off += NCB;
        uint4* srec = (uint4*)(ws + off); off += (size_t)NPAIRS * 4;
        float* part = ws + off;

        conv_feat_kernel<<<NROWS * FSIZE / 4 / 256, 256, 0, stream>>>(feat, feat16, cnt);
        if (tierA)
            conv_w1_hist_kernel<<<(NCODES * W1STRIDE / 4 + 255) / 256, 256, 0, stream>>>(
                w1, w116, idx0, cnt);
        else
            hist_kernel<<<(NPAIRS + 255) / 256, 256, 0, stream>>>(idx0, cnt);
        scan_kernel<<<1, 1024, 0, stream>>>(cnt, cursor);
        scatter_kernel<<<(NPAIRS + 255) / 256, 256, 0, stream>>>(idx0, y0, cursor, srec);
        if (tierA)
            main_kernel<true><<<NB0 + NB1, 256, 0, stream>>>(
                feat16, w0, w1, w116, srec, idx1, y1, out, part);
        else
            main_kernel<false><<<NB0 + NB1, 256, 0, stream>>>(
                feat16, w0, w1, nullptr, srec, idx1, y1, out, part);
        reduce_kernel<<<1, 1024, 0, stream>>>(part, NPART, out + NPAIRS);
    } else {
        float* part = ws;
        const int nb0 = NPAIRS / 4;
        const int nb1 = NPAIRS / 16;
        task0_kernel<<<nb0, 256, 0, stream>>>(feat, w0, idx0, y0, out, part);
        task1_kernel<<<nb1, 256, 0, stream>>>(feat, w1, idx1, y1, part + nb0);
        reduce_kernel<<<1, 1024, 0, stream>>>(part, nb0 + nb1, out + NPAIRS);
    }
}

// Round 6
// 160.338 us; speedup vs baseline: 1.9695x; 1.1664x over previous
//
#include <hip/hip_runtime.h>
#include <hip/hip_fp16.h>

#define FSIZE   768
#define TW0     769
#define TW1     193
#define COL1    576
#define NPAIRS  300000
#define NCODES  30000
#define NROWS   8192
#define W1STRIDE 200
#define NCB     32768
#define NWAVES0 (NPAIRS / 16)               // 18750 (16 pairs/wave)
#define NB0     ((NWAVES0 + 3) / 4)         // 4688
#define NB1     (NPAIRS / 32)               // 9375 (32 pairs/block)
#define NPART   (NB0 + NB1)                 // 14063

#define SZ_FEAT16 (NROWS * FSIZE / 2)       // 4B units
#define SZ_W116   (NCODES * W1STRIDE / 2)

typedef _Float16 h2_t __attribute__((ext_vector_type(2)));

#if defined(__has_builtin)
# if __has_builtin(__builtin_amdgcn_fdot2)
#  define HAVE_FDOT2 1
# endif
#endif

__device__ __forceinline__ float fdot2f(h2_t a, h2_t b, float c) {
#ifdef HAVE_FDOT2
    return __builtin_amdgcn_fdot2(a, b, c, false);
#else
    return (float)a[0] * (float)b[0] + (float)a[1] * (float)b[1] + c;
#endif
}

__device__ __forceinline__ float loss_term(float x, float y) {
    float ax = fabsf(x);
    return fmaxf(x, 0.0f) + log1pf(__expf(-ax)) - x * y;
}

__device__ __forceinline__ float4 ld4u(const float* p) {
    float4 v; __builtin_memcpy(&v, p, 16); return v;
}

// 8 fp16 (uint4) fma-accumulated against 8 f32 (2x float4)
__device__ __forceinline__ float acc8(uint4 u, float4 wa, float4 wb, float s) {
    h2_t h0, h1, h2v, h3;
    __builtin_memcpy(&h0, &u.x, 4);
    __builtin_memcpy(&h1, &u.y, 4);
    __builtin_memcpy(&h2v, &u.z, 4);
    __builtin_memcpy(&h3, &u.w, 4);
    s += (float)h0[0] * wa.x; s += (float)h0[1] * wa.y;
    s += (float)h1[0] * wa.z; s += (float)h1[1] * wa.w;
    s += (float)h2v[0] * wb.x; s += (float)h2v[1] * wb.y;
    s += (float)h3[0] * wb.z; s += (float)h3[1] * wb.w;
    return s;
}

// 8 fp16 dot 8 fp16 via fdot2
__device__ __forceinline__ float dot8hh(uint4 a, uint4 b, float s) {
    h2_t a0, a1, a2, a3, b0, b1, b2, b3;
    __builtin_memcpy(&a0, &a.x, 4); __builtin_memcpy(&a1, &a.y, 4);
    __builtin_memcpy(&a2, &a.z, 4); __builtin_memcpy(&a3, &a.w, 4);
    __builtin_memcpy(&b0, &b.x, 4); __builtin_memcpy(&b1, &b.y, 4);
    __builtin_memcpy(&b2, &b.z, 4); __builtin_memcpy(&b3, &b.w, 4);
    s = fdot2f(a0, b0, s); s = fdot2f(a1, b1, s);
    s = fdot2f(a2, b2, s); s = fdot2f(a3, b3, s);
    return s;
}

// K1: feat f32 -> fp16, fused with histogram zeroing
__global__ __launch_bounds__(256) void conv_feat_kernel(
    const float* __restrict__ in, __half* __restrict__ out, int* __restrict__ cnt)
{
    const int gid = blockIdx.x * 256 + threadIdx.x;
    const int i = gid * 4;
    if (i < NROWS * FSIZE) {
        float4 v = *(const float4*)(in + i);
        __half2* o = (__half2*)(out + i);
        o[0] = __floats2half2_rn(v.x, v.y);
        o[1] = __floats2half2_rn(v.z, v.w);
    }
    if (gid < NCB) cnt[gid] = 0;
}

// K2: w1 f32 -> fp16 (stride 200), fused with task0-code histogram
__global__ __launch_bounds__(256) void conv_w1_hist_kernel(
    const float* __restrict__ w1, __half* __restrict__ out,
    const int* __restrict__ idx0, int* __restrict__ cnt)
{
    const int gid = blockIdx.x * 256 + threadIdx.x;
    const int i4 = gid * 4;
    if (i4 < NCODES * W1STRIDE) {
        const int c = i4 / W1STRIDE;
        const int e = i4 - c * W1STRIDE;
        const float* src = w1 + (size_t)c * TW1;
        float v0 = 0.f, v1 = 0.f, v2 = 0.f, v3 = 0.f;
        if (e + 3 < TW1) {
            float4 f = ld4u(src + e);
            v0 = f.x; v1 = f.y; v2 = f.z; v3 = f.w;
        } else {
            if (e     < TW1) v0 = src[e];
            if (e + 1 < TW1) v1 = src[e + 1];
            if (e + 2 < TW1) v2 = src[e + 2];
        }
        __half2* dst = (__half2*)(out + i4);
        dst[0] = __floats2half2_rn(v0, v1);
        dst[1] = __floats2half2_rn(v2, v3);
    }
    if (gid < NPAIRS) atomicAdd(&cnt[idx0[2 * gid + 1]], 1);
}

__global__ __launch_bounds__(256) void hist_kernel(const int* __restrict__ idx,
                                                   int* __restrict__ cnt) {
    int p = blockIdx.x * 256 + threadIdx.x;
    if (p < NPAIRS) atomicAdd(&cnt[idx[2 * p + 1]], 1);
}

// K3: exclusive scan of 32768 bins — shfl-based, 2 barriers
__global__ __launch_bounds__(1024) void scan_kernel(const int* __restrict__ cnt,
                                                    int* __restrict__ cursor) {
    __shared__ int wsum[16];
    __shared__ int wbase[16];
    const int t = threadIdx.x;
    const int lane = t & 63, wv = t >> 6;
    const int4* c4 = (const int4*)cnt + t * 8;
    int4 v[8];
#pragma unroll
    for (int j = 0; j < 8; ++j) v[j] = c4[j];
    int loc[32];
    int s = 0;
#pragma unroll
    for (int j = 0; j < 8; ++j) {
        loc[4 * j + 0] = s; s += v[j].x;
        loc[4 * j + 1] = s; s += v[j].y;
        loc[4 * j + 2] = s; s += v[j].z;
        loc[4 * j + 3] = s; s += v[j].w;
    }
    int incl = s;
#pragma unroll
    for (int off = 1; off < 64; off <<= 1) {
        int u = __shfl_up(incl, off, 64);
        if (lane >= off) incl += u;
    }
    if (lane == 63) wsum[wv] = incl;
    __syncthreads();
    if (wv == 0 && lane < 16) {
        int mysum = wsum[lane];
        int winc = mysum;
#pragma unroll
        for (int off = 1; off < 16; off <<= 1) {
            int u = __shfl_up(winc, off, 64);
            if (lane >= off) winc += u;
        }
        wbase[lane] = winc - mysum;
    }
    __syncthreads();
    const int base = wbase[wv] + incl - s;
    int4* cu = (int4*)cursor + t * 8;
#pragma unroll
    for (int j = 0; j < 8; ++j)
        cu[j] = make_int4(base + loc[4 * j], base + loc[4 * j + 1],
                          base + loc[4 * j + 2], base + loc[4 * j + 3]);
}

// K4: scatter packed records {r, c, y_bits, p}
__global__ __launch_bounds__(256) void scatter_kernel(
    const int* __restrict__ idx, const float* __restrict__ y,
    int* __restrict__ cursor, uint4* __restrict__ srec)
{
    int p = blockIdx.x * 256 + threadIdx.x;
    if (p < NPAIRS) {
        int r = idx[2 * p];
        int c = idx[2 * p + 1];
        int pos = atomicAdd(&cursor[c], 1);
        srec[pos] = make_uint4((unsigned)r, (unsigned)c, __float_as_uint(y[p]), (unsigned)p);
    }
}

// K5: merged main. Blocks [0,NB0): task0 — 16-lane groups, 4 pairs/wave in
// flight, contiguous sorted spans per group, w0 f32 register-cached per run.
// Blocks [NB0,NB0+NB1): task1 — 8-lane groups, uint4 both sides.
template <bool W1H>
__global__ __launch_bounds__(256, 4) void main_kernel(
    const __half* __restrict__ feat16, const float* __restrict__ w0,
    const float* __restrict__ w1f, const __half* __restrict__ w116,
    const uint4* __restrict__ srec,
    const int* __restrict__ idx1, const float* __restrict__ y1,
    float* __restrict__ out_final, float* __restrict__ partial)
{
    __shared__ float bsum[4];
    const int lane = threadIdx.x & 63;
    const int wv   = threadIdx.x >> 6;
    float wavesum = 0.f;

    if (blockIdx.x < NB0) {
        const int wid = blockIdx.x * 4 + wv;
        if (wid < NWAVES0) {
            const int g = lane >> 4, sub = lane & 15;
            // lane (g, sub) holds record of pair base + 4g + (sub&3)
            const uint4 rec = srec[wid * 16 + 4 * g + (sub & 3)];
            int prev_c = -1;
            float4 wc[12];
            float wb = 0.f;
            float lg = 0.f;
#pragma unroll
            for (int j = 0; j < 4; ++j) {
                const int src = (lane & 48) | j;            // lane g*16+j
                const int r = __shfl((int)rec.x, src, 64);
                const int c = __shfl((int)rec.y, src, 64);
                if (c != prev_c) {                          // group-uniform, divergent across groups
                    prev_c = c;
                    const float* wrow = w0 + (size_t)c * TW0 + 8 * sub;
#pragma unroll
                    for (int k = 0; k < 6; ++k) {
                        wc[2 * k]     = ld4u(wrow + 128 * k);
                        wc[2 * k + 1] = ld4u(wrow + 128 * k + 4);
                    }
                    wb = w0[(size_t)c * TW0 + FSIZE];
                }
                const __half* fr = feat16 + (size_t)r * FSIZE + 8 * sub;
                float s = 0.f;
#pragma unroll
                for (int k = 0; k < 6; ++k) {
                    uint4 u = *(const uint4*)(fr + 128 * k);
                    s = acc8(u, wc[2 * k], wc[2 * k + 1], s);
                }
                s += __shfl_xor(s, 8, 64);
                s += __shfl_xor(s, 4, 64);
                s += __shfl_xor(s, 2, 64);
                s += __shfl_xor(s, 1, 64);
                s += wb;
                lg = (sub == j) ? s : lg;                   // park pair 4g+j in lane (g,j)
            }
            float ll = 0.f;
            if (sub < 4) {                                  // lane holds its own rec + logit
                out_final[rec.w] = lg;
                ll = loss_term(lg, __uint_as_float(rec.z));
            }
#pragma unroll
            for (int m = 32; m; m >>= 1) ll += __shfl_xor(ll, m, 64);
            wavesum = ll;
        }
    } else {
        const int bid  = blockIdx.x - NB0;
        const int sub  = lane & 7;
        const int pair = (bid * 4 + wv) * 8 + (lane >> 3);
        const int r = idx1[2 * pair];
        const int c = idx1[2 * pair + 1];
        const __half* fr = feat16 + (size_t)r * FSIZE + COL1 + 8 * sub;
        float s = 0.f;
        float bias;
        if (W1H) {
            const __half* wr = w116 + (size_t)c * W1STRIDE + 8 * sub;
#pragma unroll
            for (int k = 0; k < 3; ++k) {
                uint4 uf = *(const uint4*)(fr + 64 * k);
                uint4 uw = *(const uint4*)(wr + 64 * k);
                s = dot8hh(uf, uw, s);
            }
            bias = __half2float(w116[(size_t)c * W1STRIDE + 192]);
        } else {
            const float* wr = w1f + (size_t)c * TW1 + 8 * sub;
#pragma unroll
            for (int k = 0; k < 3; ++k) {
                uint4 uf = *(const uint4*)(fr + 64 * k);
                s = acc8(uf, ld4u(wr + 64 * k), ld4u(wr + 64 * k + 4), s);
            }
            bias = w1f[(size_t)c * TW1 + 192];
        }
        s += __shfl_xor(s, 4, 64);
        s += __shfl_xor(s, 2, 64);
        s += __shfl_xor(s, 1, 64);
        float ll = (sub == 0) ? loss_term(s + bias, y1[pair]) : 0.f;
#pragma unroll
        for (int m = 32; m; m >>= 1) ll += __shfl_xor(ll, m, 64);
        wavesum = ll;
    }

    if (lane == 0) bsum[wv] = wavesum;
    __syncthreads();
    if (threadIdx.x == 0)
        partial[blockIdx.x] = bsum[0] + bsum[1] + bsum[2] + bsum[3];
}

__global__ __launch_bounds__(1024) void reduce_kernel(
    const float* __restrict__ partial, int n, float* __restrict__ out)
{
    __shared__ float sh[1024];
    float s = 0.0f;
    for (int i = threadIdx.x; i < n; i += 1024) s += partial[i];
    sh[threadIdx.x] = s;
    __syncthreads();
    for (int off = 512; off; off >>= 1) {
        if ((int)threadIdx.x < off) sh[threadIdx.x] += sh[threadIdx.x + off];
        __syncthreads();
    }
    if (threadIdx.x == 0) out[0] = sh[0];
}

// ---------------- tier C fallback (all-f32, unsorted) ----------------
__global__ __launch_bounds__(256) void task0_kernel(
    const float* __restrict__ feat, const float* __restrict__ wt,
    const int* __restrict__ idx, const float* __restrict__ y,
    float* __restrict__ out_final, float* __restrict__ partial)
{
    __shared__ float lsum[4];
    const int lane = threadIdx.x & 63;
    const int wv = threadIdx.x >> 6;
    const int pair = blockIdx.x * 4 + wv;
    const int r = idx[2 * pair];
    const int c = idx[2 * pair + 1];
    const float4* f4 = (const float4*)(feat + (size_t)r * FSIZE);
    const float* wrow = wt + (size_t)c * TW0;
    float s = 0.0f;
#pragma unroll
    for (int k = 0; k < 3; ++k) {
        const int j = lane + (k << 6);
        float4 f = f4[j];
        float4 w = ld4u(wrow + 4 * j);
        s += f.x * w.x + f.y * w.y + f.z * w.z + f.w * w.w;
    }
#pragma unroll
    for (int m = 32; m; m >>= 1) s += __shfl_xor(s, m, 64);
    if (lane == 0) {
        const float logit = s + wrow[FSIZE];
        out_final[pair] = logit;
        lsum[wv] = loss_term(logit, y[pair]);
    }
    __syncthreads();
    if (threadIdx.x == 0)
        partial[blockIdx.x] = lsum[0] + lsum[1] + lsum[2] + lsum[3];
}

__global__ __launch_bounds__(256) void task1_kernel(
    const float* __restrict__ feat, const float* __restrict__ wt,
    const int* __restrict__ idx, const float* __restrict__ y,
    float* __restrict__ partial)
{
    __shared__ float lsum[16];
    const int lane = threadIdx.x & 63;
    const int wv = threadIdx.x >> 6;
    const int sub = lane & 15;
    const int pg = lane >> 4;
    const int pair = (blockIdx.x * 4 + wv) * 4 + pg;
    const int r = idx[2 * pair];
    const int c = idx[2 * pair + 1];
    const float4* f4 = (const float4*)(feat + (size_t)r * FSIZE + COL1);
    const float* wrow = wt + (size_t)c * TW1;
    float s = 0.0f;
#pragma unroll
    for (int k = 0; k < 3; ++k) {
        const int j = sub + (k << 4);
        float4 f = f4[j];
        float4 w = ld4u(wrow + 4 * j);
        s += f.x * w.x + f.y * w.y + f.z * w.z + f.w * w.w;
    }
#pragma unroll
    for (int m = 8; m; m >>= 1) s += __shfl_xor(s, m, 64);
    if (sub == 0) {
        const float logit = s + wrow[TW1 - 1];
        lsum[wv * 4 + pg] = loss_term(logit, y[pair]);
    }
    __syncthreads();
    if (threadIdx.x == 0) {
        float t = 0.0f;
#pragma unroll
        for (int i = 0; i < 16; ++i) t += lsum[i];
        partial[blockIdx.x] = t;
    }
}

extern "C" void kernel_launch(void* const* d_in, const int* in_sizes, int n_in,
                              void* d_out, int out_size, void* d_ws, size_t ws_size,
                              hipStream_t stream) {
    const float* feat = (const float*)d_in[0];
    const float* w0   = (const float*)d_in[1];
    const float* w1   = (const float*)d_in[2];
    const int*   idx0 = (const int*)d_in[3];
    const float* y0   = (const float*)d_in[4];
    const int*   idx1 = (const int*)d_in[6];
    const float* y1   = (const float*)d_in[7];

    float* out = (float*)d_out;
    float* ws  = (float*)d_ws;

    const size_t commonU = (size_t)NCB * 2 + (size_t)NPAIRS * 4 + NPART + 64;
    const size_t needA = (SZ_FEAT16 + SZ_W116 + commonU) * 4;
    const size_t needB = (SZ_FEAT16 + commonU) * 4;

    if (ws_size >= needB) {
        const bool tierA = (ws_size >= needA);
        size_t off = 0;
        __half* feat16 = (__half*)(ws + off); off += SZ_FEAT16;
        __half* w116 = nullptr;
        if (tierA) { w116 = (__half*)(ws + off); off += SZ_W116; }
        int* cnt    = (int*)(ws + off); off += NCB;
        int* cursor = (int*)(ws + off); off += NCB;
        uint4* srec = (uint4*)(ws + off); off += (size_t)NPAIRS * 4;
        float* part = ws + off;

        conv_feat_kernel<<<NROWS * FSIZE / 4 / 256, 256, 0, stream>>>(feat, feat16, cnt);
        if (tierA)
            conv_w1_hist_kernel<<<(NCODES * W1STRIDE / 4 + 255) / 256, 256, 0, stream>>>(
                w1, w116, idx0, cnt);
        else
            hist_kernel<<<(NPAIRS + 255) / 256, 256, 0, stream>>>(idx0, cnt);
        scan_kernel<<<1, 1024, 0, stream>>>(cnt, cursor);
        scatter_kernel<<<(NPAIRS + 255) / 256, 256, 0, stream>>>(idx0, y0, cursor, srec);
        if (tierA)
            main_kernel<true><<<NB0 + NB1, 256, 0, stream>>>(
                feat16, w0, w1, w116, srec, idx1, y1, out, part);
        else
            main_kernel<false><<<NB0 + NB1, 256, 0, stream>>>(
                feat16, w0, w1, nullptr, srec, idx1, y1, out, part);
        reduce_kernel<<<1, 1024, 0, stream>>>(part, NPART, out + NPAIRS);
    } else {
        float* part = ws;
        const int nb0 = NPAIRS / 4;
        const int nb1 = NPAIRS / 16;
        task0_kernel<<<nb0, 256, 0, stream>>>(feat, w0, idx0, y0, out, part);
        task1_kernel<<<nb1, 256, 0, stream>>>(feat, w1, idx1, y1, part + nb0);
        reduce_kernel<<<1, 1024, 0, stream>>>(part, nb0 + nb1, out + NPAIRS);
    }
}